// Round 3
// baseline (1098.930 us; speedup 1.0000x reference)
//
#include <hip/hip_runtime.h>

typedef unsigned short ushort_t;

#define NN 10000
#define BB 8
#define TT 12
#define FF 8
#define HH 64
#define GG 192   // 3H
#define HORZ 12
#define EE 320000
#define MM (BB*NN) // 80000

// ---- ws layout (float words) ----
#define OFF_H    0u
#define OFF_F1   5120000u
#define OFF_F2   10240000u
#define OFF_B1   15360000u
#define OFF_B2   20480000u
#define OFF_BIAS 25600000u
#define OFF_W1   27520000u
#define OFF_DEGF 27521536u
#define OFF_DEGB 27531536u
#define OFF_CNTF 27541536u
#define OFF_CNTB 27551536u
#define OFF_PTRF 27561536u
#define OFF_PTRB 27571537u
#define OFF_SRCF 27581538u
#define OFF_SRCB 27901538u
#define OFF_WF   28221538u
#define OFF_WB   28541538u
#define OFF_FLAG 28861538u

__device__ __forceinline__ float f4c(const float4& v, int kk) {
    switch (kk) { case 0: return v.x; case 1: return v.y; case 2: return v.z; default: return v.w; }
}
#define FMA4(ACC, W, S) \
    ACC[0] = fmaf(S, W.x, ACC[0]); \
    ACC[1] = fmaf(S, W.y, ACC[1]); \
    ACC[2] = fmaf(S, W.z, ACC[2]); \
    ACC[3] = fmaf(S, W.w, ACC[3]);

// ---------------- utility ----------------
__global__ void zero_k(float* p, int n) {
    int i = blockIdx.x * 256 + threadIdx.x;
    if (i < n) p[i] = 0.f;
}

// detect whether edge_index buffer is int64 (odd 32-bit words all zero) or int32
__global__ void flag_k(const int* __restrict__ ei, int* flag) {
    if (threadIdx.x == 0 && blockIdx.x == 0) {
        int o = ei[1] | ei[3] | ei[5] | ei[7] | ei[9] | ei[11] | ei[13];
        flag[0] = (o == 0) ? 1 : 0;
    }
}

__device__ __forceinline__ void load_edge(const int* __restrict__ ei, int isI64,
                                          int e, int& s, int& t) {
    if (isI64) {
        const long long* p = (const long long*)ei;
        s = (int)p[e]; t = (int)p[EE + e];
    } else {
        s = ei[e]; t = ei[EE + e];
    }
}

// ---------------- CSR build ----------------
__global__ void csr_count_k(const int* __restrict__ ei, const float* __restrict__ ew,
                            const int* __restrict__ flag,
                            int* cnt_f, int* cnt_b, float* deg_f, float* deg_b) {
    int e = blockIdx.x * 256 + threadIdx.x;
    if (e >= EE) return;
    int isI64 = flag[0];
    int s, t; load_edge(ei, isI64, e, s, t);
    if ((unsigned)s >= NN || (unsigned)t >= NN) return;
    float w = ew[e];
    atomicAdd(&cnt_f[t], 1); atomicAdd(&deg_f[t], w);
    atomicAdd(&cnt_b[s], 1); atomicAdd(&deg_b[s], w);
}

__global__ void scan_k(int* cnt_f, int* cnt_b, int* ptr_f, int* ptr_b) {
    int* cnt = blockIdx.x ? cnt_b : cnt_f;
    int* ptr = blockIdx.x ? ptr_b : ptr_f;
    __shared__ int part[256];
    int tid = threadIdx.x;
    const int CH = (NN + 255) / 256;
    int lo = tid * CH, hi = lo + CH; if (hi > NN) hi = NN; if (lo > NN) lo = NN;
    int s = 0;
    for (int i = lo; i < hi; i++) s += cnt[i];
    part[tid] = s;
    __syncthreads();
    if (tid == 0) {
        int run = 0;
        for (int i = 0; i < 256; i++) { int v = part[i]; part[i] = run; run += v; }
        ptr[NN] = run;
    }
    __syncthreads();
    int run = part[tid];
    for (int i = lo; i < hi; i++) { ptr[i] = run; run += cnt[i]; cnt[i] = 0; }
}

__global__ void csr_fill_k(const int* __restrict__ ei, const float* __restrict__ ew,
                           const int* __restrict__ flag,
                           const float* __restrict__ deg_f, const float* __restrict__ deg_b,
                           const int* __restrict__ ptr_f, const int* __restrict__ ptr_b,
                           int* cnt_f, int* cnt_b,
                           int* src_f, int* src_b, float* w_f, float* w_b) {
    int e = blockIdx.x * 256 + threadIdx.x;
    if (e >= EE) return;
    int isI64 = flag[0];
    int s, t; load_edge(ei, isI64, e, s, t);
    if ((unsigned)s >= NN || (unsigned)t >= NN) return;
    float w = ew[e];
    float df = deg_f[t];
    float nwf = w / ((df == 0.f) ? 1.f : df);
    int p = ptr_f[t] + atomicAdd(&cnt_f[t], 1);
    src_f[p] = s; w_f[p] = nwf;
    float db = deg_b[s];
    float nwb = w / ((db == 0.f) ? 1.f : db);
    int p2 = ptr_b[s] + atomicAdd(&cnt_b[s], 1);
    src_b[p2] = t; w_b[p2] = nwb;
}

// ---------------- precompute W1 = enc_W @ Wih^T  [8][192] ----------------
__global__ void w1_k(const float* __restrict__ encW, const float* __restrict__ wih,
                     float* __restrict__ W1) {
    int id = blockIdx.x * 256 + threadIdx.x;
    if (id >= FF * GG) return;
    int f = id / GG, g = id - f * GG;
    float acc = 0.f;
    for (int hh = 0; hh < HH; hh++)
        acc = fmaf(encW[f * HH + hh], wih[g * HH + hh], acc);
    W1[id] = acc;
}

// ---- biasA[n][g] = bih[g] + (g<128? bhh[g]:0) + sum_h (enc_b+emb[n])*Wih[g][h] ----
__global__ __launch_bounds__(256)
void biasA_k(const float* __restrict__ emb, const float* __restrict__ encb,
             const float* __restrict__ wih, const float* __restrict__ bih,
             const float* __restrict__ bhh, float* __restrict__ biasA) {
    __shared__ float wl[HH * GG]; // wl[h][g] = Wih[g][h]
    __shared__ float eb[HH];
    int tid = threadIdx.x;
    for (int idx = tid * 4; idx < GG * HH; idx += 1024) {
        float4 v = *(const float4*)&wih[idx];
        int g = idx >> 6, hh = idx & 63;
        wl[hh * GG + g] = v.x;
        wl[(hh + 1) * GG + g] = v.y;
        wl[(hh + 2) * GG + g] = v.z;
        wl[(hh + 3) * GG + g] = v.w;
    }
    if (tid < HH) eb[tid] = encb[tid];
    __syncthreads();
    int id = blockIdx.x * 256 + tid;
    if (id >= NN * GG) return;
    int n = id / GG, g = id - n * GG;
    float acc = bih[g];
    if (g < 128) acc += bhh[g];
    const float* ep = emb + n * HH;
    for (int hh = 0; hh < HH; hh++)
        acc = fmaf(eb[hh] + ep[hh], wl[hh * GG + g], acc);
    biasA[id] = acc;
}

// ---------------- fused GRU (all 12 steps per block) ----------------
__global__ __launch_bounds__(256, 2)
void gru_k(const float* __restrict__ x, const float* __restrict__ biasA,
           const float* __restrict__ W1, const float* __restrict__ whh,
           const float* __restrict__ bhh, float* __restrict__ h_out) {
    __shared__ float lds_w[64 * 196];  // Whh^T: [k][g], stride 196
    __shared__ float lds_w1[8 * 192];  // W1 [f][g]
    __shared__ float lds_h[64 * 68];   // h tile [row][k], stride 68
    __shared__ float lds_x[64 * 8];    // x tile fp32

    const int tid = threadIdx.x;
    const int m0 = blockIdx.x * 64;
    const int cgrp = tid & 15, rgrp = tid >> 4;
    const int c0 = cgrp * 4, r0 = rgrp * 4;

    // stage Whh transposed
    for (int idx = tid * 4; idx < GG * HH; idx += 1024) {
        float4 v = *(const float4*)&whh[idx];
        int g = idx >> 6, k = idx & 63;
        lds_w[k * 196 + g] = v.x;
        lds_w[(k + 1) * 196 + g] = v.y;
        lds_w[(k + 2) * 196 + g] = v.z;
        lds_w[(k + 3) * 196 + g] = v.w;
    }
    for (int idx = tid; idx < 8 * GG; idx += 256) lds_w1[idx] = W1[idx];

    // per-thread constant biases
    float bR[4][4], bZ[4][4], bXn[4][4], bHn[4];
    #pragma unroll
    for (int i = 0; i < 4; i++) {
        int m = m0 + r0 + i;
        int b = m / NN; int n = m - b * NN;
        const float4 vr = *(const float4*)&biasA[n * GG + c0];
        const float4 vz = *(const float4*)&biasA[n * GG + 64 + c0];
        const float4 vn = *(const float4*)&biasA[n * GG + 128 + c0];
        bR[i][0] = vr.x; bR[i][1] = vr.y; bR[i][2] = vr.z; bR[i][3] = vr.w;
        bZ[i][0] = vz.x; bZ[i][1] = vz.y; bZ[i][2] = vz.z; bZ[i][3] = vz.w;
        bXn[i][0] = vn.x; bXn[i][1] = vn.y; bXn[i][2] = vn.z; bXn[i][3] = vn.w;
    }
    #pragma unroll
    for (int j = 0; j < 4; j++) bHn[j] = bhh[128 + c0 + j];

    float hprev[4][4];
    #pragma unroll
    for (int i = 0; i < 4; i++)
        #pragma unroll
        for (int j = 0; j < 4; j++) hprev[i][j] = 0.f;

    #pragma unroll 1
    for (int t = 0; t < TT; t++) {
        __syncthreads(); // staging + prev-step lds_h writes + prev lds_x readers done
        if (tid < 64) {
            int m = m0 + tid;
            int b = m / NN; int n = m - b * NN;
            const float* xp = x + ((size_t)(b * TT + t) * NN + n) * FF;
            float4 v0 = *(const float4*)xp;
            float4 v1 = *(const float4*)(xp + 4);
            *(float4*)&lds_x[tid * 8]     = v0;
            *(float4*)&lds_x[tid * 8 + 4] = v1;
        }
        float ar[4][4], az[4][4], axn[4][4], ahn[4][4];
        #pragma unroll
        for (int i = 0; i < 4; i++)
            #pragma unroll
            for (int j = 0; j < 4; j++) {
                ar[i][j] = bR[i][j]; az[i][j] = bZ[i][j];
                axn[i][j] = bXn[i][j]; ahn[i][j] = bHn[j];
            }
        __syncthreads(); // lds_x ready

        // gx contribution (K=8)
        #pragma unroll
        for (int f = 0; f < 8; f++) {
            const float4 wr = *(const float4*)&lds_w1[f * GG + c0];
            const float4 wz = *(const float4*)&lds_w1[f * GG + 64 + c0];
            const float4 wn = *(const float4*)&lds_w1[f * GG + 128 + c0];
            #pragma unroll
            for (int i = 0; i < 4; i++) {
                float xv = lds_x[(r0 + i) * 8 + f];
                FMA4(ar[i], wr, xv);
                FMA4(az[i], wz, xv);
                FMA4(axn[i], wn, xv);
            }
        }
        // gh contribution (K=64)
        if (t > 0) {
            #pragma unroll 4
            for (int k4 = 0; k4 < 64; k4 += 4) {
                float4 hv[4];
                #pragma unroll
                for (int i = 0; i < 4; i++)
                    hv[i] = *(const float4*)&lds_h[(r0 + i) * 68 + k4];
                #pragma unroll
                for (int kk = 0; kk < 4; kk++) {
                    const float4 wr = *(const float4*)&lds_w[(k4 + kk) * 196 + c0];
                    const float4 wz = *(const float4*)&lds_w[(k4 + kk) * 196 + 64 + c0];
                    const float4 wn = *(const float4*)&lds_w[(k4 + kk) * 196 + 128 + c0];
                    #pragma unroll
                    for (int i = 0; i < 4; i++) {
                        float hk = f4c(hv[i], kk);
                        FMA4(ar[i], wr, hk);
                        FMA4(az[i], wz, hk);
                        FMA4(ahn[i], wn, hk);
                    }
                }
            }
        }
        // gates
        float hnew[4][4];
        #pragma unroll
        for (int i = 0; i < 4; i++)
            #pragma unroll
            for (int j = 0; j < 4; j++) {
                float rr = 1.f / (1.f + __expf(-ar[i][j]));
                float zz = 1.f / (1.f + __expf(-az[i][j]));
                float pre = fmaf(rr, ahn[i][j], axn[i][j]);
                pre = fminf(fmaxf(pre, -30.f), 30.f);
                float e2 = __expf(pre + pre);
                float nn = (e2 - 1.f) / (e2 + 1.f);
                hnew[i][j] = (1.f - zz) * nn + zz * hprev[i][j];
            }
        __syncthreads(); // all lds_h reads of this step done
        #pragma unroll
        for (int i = 0; i < 4; i++) {
            *(float4*)&lds_h[(r0 + i) * 68 + c0] =
                make_float4(hnew[i][0], hnew[i][1], hnew[i][2], hnew[i][3]);
            #pragma unroll
            for (int j = 0; j < 4; j++) hprev[i][j] = hnew[i][j];
        }
    }
    // final h from registers
    #pragma unroll
    for (int i = 0; i < 4; i++) {
        int m = m0 + r0 + i;
        *(float4*)&h_out[m * HH + c0] =
            make_float4(hprev[i][0], hprev[i][1], hprev[i][2], hprev[i][3]);
    }
}

// ---------------- diffusion propagation (CSR, no atomics) ----------------
__global__ void prop_k(const float* __restrict__ src, float* __restrict__ dst,
                       const int* __restrict__ ptr, const int* __restrict__ nbr,
                       const float* __restrict__ w) {
    int t = blockIdx.x, lane = threadIdx.x;
    float acc[8] = {0.f, 0.f, 0.f, 0.f, 0.f, 0.f, 0.f, 0.f};
    int e0 = ptr[t], e1 = ptr[t + 1];
    for (int e = e0; e < e1; e++) {
        int s = nbr[e]; float wv = w[e];
        const float* sp = src + s * HH + lane;
        #pragma unroll
        for (int b = 0; b < 8; b++)
            acc[b] = fmaf(sp[b * NN * HH], wv, acc[b]);
    }
    #pragma unroll
    for (int b = 0; b < 8; b++)
        dst[(b * NN + t) * HH + lane] = acc[b];
}

// ---------------- fused filter (K=320) + decoder (K=64) ----------------
__global__ __launch_bounds__(256, 2)
void filtdec_k(const float* __restrict__ h, const float* __restrict__ f1,
               const float* __restrict__ f2, const float* __restrict__ b1,
               const float* __restrict__ b2,
               const float* __restrict__ filtW, const float* __restrict__ filtb,
               const float* __restrict__ decW, const float* __restrict__ decb,
               float* __restrict__ out) {
    __shared__ float lds_in[64 * 100]; // src tiles; later out staging
    __shared__ float lds_w[64 * 100];  // filtW chunk, later decW
    __shared__ float lds_z[64 * 68];
    const int tid = threadIdx.x;
    const int m0 = blockIdx.x * 64;
    const int cgrp = tid & 15, rgrp = tid >> 4;
    const int c0 = cgrp * 4, r0 = rgrp * 4;

    float acc[4][4];
    #pragma unroll
    for (int i = 0; i < 4; i++)
        #pragma unroll
        for (int j = 0; j < 4; j++) acc[i][j] = 0.f;

    #pragma unroll 1
    for (int q = 0; q < 5; q++) {
        const float* src = (q == 0) ? h : (q == 1) ? f1 : (q == 2) ? f2 : (q == 3) ? b1 : b2;
        {   // load input tile 64x64 fp32
            int row = tid >> 2, cc = (tid & 3) * 16;
            const float* sp = src + (m0 + row) * HH + cc;
            float4 v0 = *(const float4*)(sp + 0);
            float4 v1 = *(const float4*)(sp + 4);
            float4 v2 = *(const float4*)(sp + 8);
            float4 v3 = *(const float4*)(sp + 12);
            *(float4*)&lds_in[row * 100 + cc + 0]  = v0;
            *(float4*)&lds_in[row * 100 + cc + 4]  = v1;
            *(float4*)&lds_in[row * 100 + cc + 8]  = v2;
            *(float4*)&lds_in[row * 100 + cc + 12] = v3;
        }
        {   // load filtW chunk rows q*64.. (fp32)
            int k = tid >> 2, cc = (tid & 3) * 16;
            const float* wp = filtW + (size_t)(q * 64 + k) * HH + cc;
            float4 v0 = *(const float4*)(wp + 0);
            float4 v1 = *(const float4*)(wp + 4);
            float4 v2 = *(const float4*)(wp + 8);
            float4 v3 = *(const float4*)(wp + 12);
            *(float4*)&lds_w[k * 100 + cc + 0]  = v0;
            *(float4*)&lds_w[k * 100 + cc + 4]  = v1;
            *(float4*)&lds_w[k * 100 + cc + 8]  = v2;
            *(float4*)&lds_w[k * 100 + cc + 12] = v3;
        }
        __syncthreads();
        #pragma unroll 4
        for (int k4 = 0; k4 < 64; k4 += 4) {
            float4 iv[4];
            #pragma unroll
            for (int i = 0; i < 4; i++)
                iv[i] = *(const float4*)&lds_in[(r0 + i) * 100 + k4];
            #pragma unroll
            for (int kk = 0; kk < 4; kk++) {
                const float4 wv = *(const float4*)&lds_w[(k4 + kk) * 100 + c0];
                #pragma unroll
                for (int i = 0; i < 4; i++) {
                    float a_ = f4c(iv[i], kk);
                    FMA4(acc[i], wv, a_);
                }
            }
        }
        __syncthreads();
    }
    // + filt_b, write z tile
    {
        float fb[4];
        #pragma unroll
        for (int j = 0; j < 4; j++) fb[j] = filtb[c0 + j];
        #pragma unroll
        for (int i = 0; i < 4; i++)
            *(float4*)&lds_z[(r0 + i) * 68 + c0] =
                make_float4(acc[i][0] + fb[0], acc[i][1] + fb[1],
                            acc[i][2] + fb[2], acc[i][3] + fb[3]);
    }
    {   // load decW [64][96] fp32 into lds_w (stride 100)
        int k = tid >> 2, cc = (tid & 3) * 24;
        const float* wp = decW + k * 96 + cc;
        float* dstp = &lds_w[k * 100 + cc];
        #pragma unroll
        for (int u = 0; u < 6; u++) {
            float4 v = *(const float4*)(wp + u * 4);
            *(float4*)(dstp + u * 4) = v;
        }
    }
    __syncthreads(); // z + decW ready

    // decoder: 16 cgroups x 6 cols
    const int c0b = (tid & 15) * 6;
    float acc2[4][6];
    #pragma unroll
    for (int i = 0; i < 4; i++)
        #pragma unroll
        for (int j = 0; j < 6; j++) acc2[i][j] = 0.f;
    #pragma unroll 4
    for (int k4 = 0; k4 < 64; k4 += 4) {
        float4 zv[4];
        #pragma unroll
        for (int i = 0; i < 4; i++)
            zv[i] = *(const float4*)&lds_z[(r0 + i) * 68 + k4];
        #pragma unroll
        for (int kk = 0; kk < 4; kk++) {
            float2 wa = *(const float2*)&lds_w[(k4 + kk) * 100 + c0b];
            float2 wb = *(const float2*)&lds_w[(k4 + kk) * 100 + c0b + 2];
            float2 wc = *(const float2*)&lds_w[(k4 + kk) * 100 + c0b + 4];
            #pragma unroll
            for (int i = 0; i < 4; i++) {
                float zz = f4c(zv[i], kk);
                acc2[i][0] = fmaf(zz, wa.x, acc2[i][0]);
                acc2[i][1] = fmaf(zz, wa.y, acc2[i][1]);
                acc2[i][2] = fmaf(zz, wb.x, acc2[i][2]);
                acc2[i][3] = fmaf(zz, wb.y, acc2[i][3]);
                acc2[i][4] = fmaf(zz, wc.x, acc2[i][4]);
                acc2[i][5] = fmaf(zz, wc.y, acc2[i][5]);
            }
        }
    }
    {   // + dec_b, stage into lds_in (as out buffer, stride 100)
        float db[6];
        #pragma unroll
        for (int j = 0; j < 6; j++) db[j] = decb[c0b + j];
        #pragma unroll
        for (int i = 0; i < 4; i++)
            #pragma unroll
            for (int j = 0; j < 6; j++)
                lds_in[(r0 + i) * 100 + c0b + j] = acc2[i][j] + db[j];
    }
    __syncthreads();
    // coalesced fp32 writes: per hor, 512 floats = 256 float2 stores
    #pragma unroll 1
    for (int hor = 0; hor < HORZ; hor++) {
        int nl = tid >> 2, fp = tid & 3;
        int m = m0 + nl;
        int b = m / NN; int n = m - b * NN;
        float v0 = lds_in[nl * 100 + hor * 8 + 2 * fp];
        float v1 = lds_in[nl * 100 + hor * 8 + 2 * fp + 1];
        *(float2*)&out[(((size_t)b * HORZ + hor) * NN + n) * FF + 2 * fp] =
            make_float2(v0, v1);
    }
}

extern "C" void kernel_launch(void* const* d_in, const int* in_sizes, int n_in,
                              void* d_out, int out_size, void* d_ws, size_t ws_size,
                              hipStream_t stream) {
    (void)in_sizes; (void)n_in; (void)out_size; (void)ws_size;
    const float* x     = (const float*)d_in[0];
    const int*   ei    = (const int*)d_in[1];
    const float* ew    = (const float*)d_in[2];
    const float* encW  = (const float*)d_in[3];
    const float* encb  = (const float*)d_in[4];
    const float* emb   = (const float*)d_in[5];
    const float* wih   = (const float*)d_in[6];
    const float* whh   = (const float*)d_in[7];
    const float* bih   = (const float*)d_in[8];
    const float* bhh   = (const float*)d_in[9];
    const float* filtW = (const float*)d_in[10];
    const float* filtb = (const float*)d_in[11];
    const float* decW  = (const float*)d_in[12];
    const float* decb  = (const float*)d_in[13];
    float* out = (float*)d_out;

    float* ws = (float*)d_ws;
    float* h    = ws + OFF_H;
    float* f1   = ws + OFF_F1;
    float* f2   = ws + OFF_F2;
    float* b1   = ws + OFF_B1;
    float* b2   = ws + OFF_B2;
    float* bias = ws + OFF_BIAS;
    float* W1   = ws + OFF_W1;
    float* degf = ws + OFF_DEGF;
    float* degb = ws + OFF_DEGB;
    int* cntf = (int*)(ws + OFF_CNTF);
    int* cntb = (int*)(ws + OFF_CNTB);
    int* ptrf = (int*)(ws + OFF_PTRF);
    int* ptrb = (int*)(ws + OFF_PTRB);
    int* srcf = (int*)(ws + OFF_SRCF);
    int* srcb = (int*)(ws + OFF_SRCB);
    float* wf = ws + OFF_WF;
    float* wb = ws + OFF_WB;
    int* flag = (int*)(ws + OFF_FLAG);

    flag_k<<<1, 64, 0, stream>>>(ei, flag);
    // zero deg_f, deg_b, cnt_f, cnt_b (contiguous 40000 words)
    zero_k<<<(40000 + 255) / 256, 256, 0, stream>>>(degf, 40000);
    csr_count_k<<<EE / 256, 256, 0, stream>>>(ei, ew, flag, cntf, cntb, degf, degb);
    scan_k<<<2, 256, 0, stream>>>(cntf, cntb, ptrf, ptrb);
    csr_fill_k<<<EE / 256, 256, 0, stream>>>(ei, ew, flag, degf, degb, ptrf, ptrb,
                                             cntf, cntb, srcf, srcb, wf, wb);
    w1_k<<<(FF * GG + 255) / 256, 256, 0, stream>>>(encW, wih, W1);
    biasA_k<<<(NN * GG) / 256, 256, 0, stream>>>(emb, encb, wih, bih, bhh, bias);
    gru_k<<<MM / 64, 256, 0, stream>>>(x, bias, W1, whh, bhh, h);
    prop_k<<<NN, 64, 0, stream>>>(h,  f1, ptrf, srcf, wf);
    prop_k<<<NN, 64, 0, stream>>>(f1, f2, ptrf, srcf, wf);
    prop_k<<<NN, 64, 0, stream>>>(h,  b1, ptrb, srcb, wb);
    prop_k<<<NN, 64, 0, stream>>>(b1, b2, ptrb, srcb, wb);
    filtdec_k<<<MM / 64, 256, 0, stream>>>(h, f1, f2, b1, b2,
                                           filtW, filtb, decW, decb, out);
}

// Round 4
// 792.470 us; speedup vs baseline: 1.3867x; 1.3867x over previous
//
#include <hip/hip_runtime.h>

typedef unsigned short ushort_t;

#define NN 10000
#define BB 8
#define TT 12
#define FF 8
#define HH 64
#define GG 192   // 3H
#define HORZ 12
#define EE 320000
#define MM (BB*NN) // 80000

// ---- ws layout (float words) ----
#define OFF_H    0u
#define OFF_F1   5120000u
#define OFF_F2   10240000u
#define OFF_B1   15360000u
#define OFF_B2   20480000u
#define OFF_BIAS 25600000u
#define OFF_W1   27520000u
#define OFF_DEGF 27521536u
#define OFF_DEGB 27531536u
#define OFF_CNTF 27541536u
#define OFF_CNTB 27551536u
#define OFF_PTRF 27561536u
#define OFF_PTRB 27571537u
#define OFF_SRCF 27581538u
#define OFF_SRCB 27901538u
#define OFF_WF   28221538u
#define OFF_WB   28541538u
#define OFF_FLAG 28861538u

typedef __attribute__((ext_vector_type(8))) short short8;
typedef __attribute__((ext_vector_type(4))) float f4v;

union I4S8 { int4 i; short8 s; };

__device__ __forceinline__ f4v mfma16(int4 a, int4 b, f4v c) {
    I4S8 ua, ub; ua.i = a; ub.i = b;
    return __builtin_amdgcn_mfma_f32_16x16x32_bf16(ua.s, ub.s, c, 0, 0, 0);
}

__device__ __forceinline__ unsigned f2bf_u(float f) {
    union { float f; unsigned u; } v; v.f = f;
    unsigned x = v.u;
    x += 0x7FFFu + ((x >> 16) & 1u);
    return x >> 16;
}
// split 8 fp32 into bf16 hi + bf16 lo fragments (packed)
__device__ __forceinline__ void hilo8(const float* f, int4& hi, int4& lo) {
    unsigned hb[8], lb[8];
    #pragma unroll
    for (int i = 0; i < 8; i++) {
        float v = f[i];
        unsigned h = f2bf_u(v);
        union { unsigned u; float fl; } bk; bk.u = h << 16;
        lb[i] = f2bf_u(v - bk.fl);
        hb[i] = h;
    }
    hi = make_int4((int)(hb[0]|(hb[1]<<16)), (int)(hb[2]|(hb[3]<<16)),
                   (int)(hb[4]|(hb[5]<<16)), (int)(hb[6]|(hb[7]<<16)));
    lo = make_int4((int)(lb[0]|(lb[1]<<16)), (int)(lb[2]|(lb[3]<<16)),
                   (int)(lb[4]|(lb[5]<<16)), (int)(lb[6]|(lb[7]<<16)));
}

__device__ __forceinline__ float f4c(const float4& v, int kk) {
    switch (kk) { case 0: return v.x; case 1: return v.y; case 2: return v.z; default: return v.w; }
}
#define FMA4(ACC, W, S) \
    ACC[0] = fmaf(S, W.x, ACC[0]); \
    ACC[1] = fmaf(S, W.y, ACC[1]); \
    ACC[2] = fmaf(S, W.z, ACC[2]); \
    ACC[3] = fmaf(S, W.w, ACC[3]);

// ---------------- utility ----------------
__global__ void zero_k(float* p, int n) {
    int i = blockIdx.x * 256 + threadIdx.x;
    if (i < n) p[i] = 0.f;
}

__global__ void flag_k(const int* __restrict__ ei, int* flag) {
    if (threadIdx.x == 0 && blockIdx.x == 0) {
        int o = ei[1] | ei[3] | ei[5] | ei[7] | ei[9] | ei[11] | ei[13];
        flag[0] = (o == 0) ? 1 : 0;
    }
}

__device__ __forceinline__ void load_edge(const int* __restrict__ ei, int isI64,
                                          int e, int& s, int& t) {
    if (isI64) {
        const long long* p = (const long long*)ei;
        s = (int)p[e]; t = (int)p[EE + e];
    } else {
        s = ei[e]; t = ei[EE + e];
    }
}

// ---------------- CSR build ----------------
__global__ void csr_count_k(const int* __restrict__ ei, const float* __restrict__ ew,
                            const int* __restrict__ flag,
                            int* cnt_f, int* cnt_b, float* deg_f, float* deg_b) {
    int e = blockIdx.x * 256 + threadIdx.x;
    if (e >= EE) return;
    int isI64 = flag[0];
    int s, t; load_edge(ei, isI64, e, s, t);
    if ((unsigned)s >= NN || (unsigned)t >= NN) return;
    float w = ew[e];
    atomicAdd(&cnt_f[t], 1); atomicAdd(&deg_f[t], w);
    atomicAdd(&cnt_b[s], 1); atomicAdd(&deg_b[s], w);
}

__global__ void scan_k(int* cnt_f, int* cnt_b, int* ptr_f, int* ptr_b) {
    int* cnt = blockIdx.x ? cnt_b : cnt_f;
    int* ptr = blockIdx.x ? ptr_b : ptr_f;
    __shared__ int part[256];
    int tid = threadIdx.x;
    const int CH = (NN + 255) / 256;
    int lo = tid * CH, hi = lo + CH; if (hi > NN) hi = NN; if (lo > NN) lo = NN;
    int s = 0;
    for (int i = lo; i < hi; i++) s += cnt[i];
    part[tid] = s;
    __syncthreads();
    if (tid == 0) {
        int run = 0;
        for (int i = 0; i < 256; i++) { int v = part[i]; part[i] = run; run += v; }
        ptr[NN] = run;
    }
    __syncthreads();
    int run = part[tid];
    for (int i = lo; i < hi; i++) { ptr[i] = run; run += cnt[i]; cnt[i] = 0; }
}

__global__ void csr_fill_k(const int* __restrict__ ei, const float* __restrict__ ew,
                           const int* __restrict__ flag,
                           const float* __restrict__ deg_f, const float* __restrict__ deg_b,
                           const int* __restrict__ ptr_f, const int* __restrict__ ptr_b,
                           int* cnt_f, int* cnt_b,
                           int* src_f, int* src_b, float* w_f, float* w_b) {
    int e = blockIdx.x * 256 + threadIdx.x;
    if (e >= EE) return;
    int isI64 = flag[0];
    int s, t; load_edge(ei, isI64, e, s, t);
    if ((unsigned)s >= NN || (unsigned)t >= NN) return;
    float w = ew[e];
    float df = deg_f[t];
    float nwf = w / ((df == 0.f) ? 1.f : df);
    int p = ptr_f[t] + atomicAdd(&cnt_f[t], 1);
    src_f[p] = s; w_f[p] = nwf;
    float db = deg_b[s];
    float nwb = w / ((db == 0.f) ? 1.f : db);
    int p2 = ptr_b[s] + atomicAdd(&cnt_b[s], 1);
    src_b[p2] = t; w_b[p2] = nwb;
}

// ---------------- precompute W1 = enc_W @ Wih^T  [8][192] ----------------
__global__ void w1_k(const float* __restrict__ encW, const float* __restrict__ wih,
                     float* __restrict__ W1) {
    int id = blockIdx.x * 256 + threadIdx.x;
    if (id >= FF * GG) return;
    int f = id / GG, g = id - f * GG;
    float acc = 0.f;
    for (int hh = 0; hh < HH; hh++)
        acc = fmaf(encW[f * HH + hh], wih[g * HH + hh], acc);
    W1[id] = acc;
}

// ---- biasA[n][g] = bih[g] + (g<128? bhh[g]:0) + sum_h (enc_b+emb[n])*Wih[g][h] ----
// tiled: 157 blocks x (64 rows x 192 cols), weights staged once per block
__global__ __launch_bounds__(256, 2)
void biasA_k(const float* __restrict__ emb, const float* __restrict__ encb,
             const float* __restrict__ wih, const float* __restrict__ bih,
             const float* __restrict__ bhh, float* __restrict__ biasA) {
    __shared__ float wl[HH * GG];   // wl[h][g] = Wih[g][h]
    __shared__ float et[64 * 68];   // enc_b + emb tile
    const int tid = threadIdx.x;
    const int n0 = blockIdx.x * 64;
    // stage Wih transposed
    for (int idx = tid * 4; idx < GG * HH; idx += 1024) {
        float4 v = *(const float4*)&wih[idx];
        int g = idx >> 6, hh = idx & 63;
        wl[hh * GG + g] = v.x;
        wl[(hh + 1) * GG + g] = v.y;
        wl[(hh + 2) * GG + g] = v.z;
        wl[(hh + 3) * GG + g] = v.w;
    }
    {   // stage enc_b + emb rows
        int row = tid >> 2, cc = (tid & 3) * 16;
        int n = n0 + row;
        #pragma unroll
        for (int u = 0; u < 4; u++) {
            float4 e4 = (n < NN) ? *(const float4*)&emb[(size_t)n * HH + cc + u * 4]
                                 : make_float4(0.f, 0.f, 0.f, 0.f);
            float4 b4 = *(const float4*)&encb[cc + u * 4];
            *(float4*)&et[row * 68 + cc + u * 4] =
                make_float4(e4.x + b4.x, e4.y + b4.y, e4.z + b4.z, e4.w + b4.w);
        }
    }
    __syncthreads();
    const int r0 = (tid >> 4) * 4;
    #pragma unroll 1
    for (int p = 0; p < 3; p++) {
        const int c0 = p * 64 + (tid & 15) * 4;
        float acc[4][4];
        float4 bi = *(const float4*)&bih[c0];
        float4 bh = (c0 < 128) ? *(const float4*)&bhh[c0] : make_float4(0.f, 0.f, 0.f, 0.f);
        #pragma unroll
        for (int i = 0; i < 4; i++) {
            acc[i][0] = bi.x + bh.x; acc[i][1] = bi.y + bh.y;
            acc[i][2] = bi.z + bh.z; acc[i][3] = bi.w + bh.w;
        }
        #pragma unroll 4
        for (int k4 = 0; k4 < 64; k4 += 4) {
            float4 hv[4];
            #pragma unroll
            for (int i = 0; i < 4; i++)
                hv[i] = *(const float4*)&et[(r0 + i) * 68 + k4];
            #pragma unroll
            for (int kk = 0; kk < 4; kk++) {
                const float4 wv = *(const float4*)&wl[(k4 + kk) * GG + c0];
                #pragma unroll
                for (int i = 0; i < 4; i++) {
                    float a_ = f4c(hv[i], kk);
                    FMA4(acc[i], wv, a_);
                }
            }
        }
        #pragma unroll
        for (int i = 0; i < 4; i++) {
            int n = n0 + r0 + i;
            if (n < NN)
                *(float4*)&biasA[(size_t)n * GG + c0] =
                    make_float4(acc[i][0], acc[i][1], acc[i][2], acc[i][3]);
        }
    }
}

// ---------------- MFMA GRU: all 12 steps, no barriers in loop ----------------
// h_out written in [n][b][64] layout for the diffusion gathers.
__global__ __launch_bounds__(256, 2)
void gru_k(const float* __restrict__ x, const float* __restrict__ biasA,
           const float* __restrict__ W1, const float* __restrict__ whh,
           const float* __restrict__ bhh, float* __restrict__ h_out) {
    __shared__ int   lds_B[24 * 64 * 4];   // Whh B-fragments, bf16 packed (24 KB)
    __shared__ float lds_h[4 * 16 * 68];   // per-wave h scratch fp32 (17.4 KB)

    const int tid = threadIdx.x;
    const int wave = tid >> 6, ln = tid & 63;
    const int quad = ln >> 4, lx = ln & 15;
    const int m0 = blockIdx.x * 64;
    const int woff = wave * 16 * 68;

    // ---- stage Whh B-fragments: frag fid=(c*2+q), lane ln, elem j =
    //      Whh^T[k = q*32 + (ln>>4)*8 + j][g = c*16 + (ln&15)] = whh[g*64 + k]
    #pragma unroll
    for (int it = 0; it < 6; it++) {
        int slot = tid + it * 256;
        int fid = slot >> 6, l2 = slot & 63;
        int c = fid >> 1, q = fid & 1;
        int g = c * 16 + (l2 & 15);
        int k0 = q * 32 + ((l2 >> 4) & 3) * 8;
        const float* wp = whh + (size_t)g * HH + k0;
        float4 v0 = *(const float4*)wp;
        float4 v1 = *(const float4*)(wp + 4);
        float fv[8] = {v0.x, v0.y, v0.z, v0.w, v1.x, v1.y, v1.z, v1.w};
        int4 pk;
        unsigned hb[8];
        #pragma unroll
        for (int j = 0; j < 8; j++) hb[j] = f2bf_u(fv[j]);
        pk = make_int4((int)(hb[0]|(hb[1]<<16)), (int)(hb[2]|(hb[3]<<16)),
                       (int)(hb[4]|(hb[5]<<16)), (int)(hb[6]|(hb[7]<<16)));
        *(int4*)&lds_B[slot * 4] = pk;
    }

    // ---- W1 B-fragments in registers (K=32 padded; only k<8 real -> lanes 0-15)
    int4 w1f[12];
    #pragma unroll
    for (int j = 0; j < 12; j++) w1f[j] = make_int4(0, 0, 0, 0);
    if (ln < 16) {
        #pragma unroll
        for (int j = 0; j < 12; j++) {
            int col = j * 16 + ln;
            unsigned hb[8];
            #pragma unroll
            for (int k = 0; k < 8; k++) hb[k] = f2bf_u(W1[k * GG + col]);
            w1f[j] = make_int4((int)(hb[0]|(hb[1]<<16)), (int)(hb[2]|(hb[3]<<16)),
                               (int)(hb[4]|(hb[5]<<16)), (int)(hb[6]|(hb[7]<<16)));
        }
    }

    // ---- per-lane biases (C-layout positions)
    f4v bR[4], bZ[4], bNx[4];
    float bHn[4];
    int rowb[4], rown[4];
    #pragma unroll
    for (int reg = 0; reg < 4; reg++) {
        int m = m0 + wave * 16 + quad * 4 + reg;
        rowb[reg] = m / NN; rown[reg] = m - rowb[reg] * NN;
    }
    #pragma unroll
    for (int j = 0; j < 4; j++) {
        int c = j * 16 + lx;
        #pragma unroll
        for (int reg = 0; reg < 4; reg++) {
            const float* bp = biasA + (size_t)rown[reg] * GG;
            bR[j][reg]  = bp[c];
            bZ[j][reg]  = bp[64 + c];
            bNx[j][reg] = bp[128 + c];
        }
        bHn[j] = bhh[128 + c];
    }

    __syncthreads();   // lds_B ready (only barrier)

    f4v hp[4];
    #pragma unroll
    for (int j = 0; j < 4; j++) hp[j] = (f4v){0.f, 0.f, 0.f, 0.f};

    #pragma unroll 1
    for (int t = 0; t < TT; t++) {
        // x A-fragment (lanes 0-15 hold k=0..7; others zero)
        int4 axh = make_int4(0,0,0,0), axl = make_int4(0,0,0,0);
        if (ln < 16) {
            int m = m0 + wave * 16 + ln;
            int b = m / NN; int n = m - b * NN;
            const float* xp = x + ((size_t)(b * TT + t) * NN + n) * FF;
            float4 v0 = *(const float4*)xp;
            float4 v1 = *(const float4*)(xp + 4);
            float fv[8] = {v0.x, v0.y, v0.z, v0.w, v1.x, v1.y, v1.z, v1.w};
            hilo8(fv, axh, axl);
        }

        // h A-fragments (2 K-halves), hi/lo
        int4 ahh[2], ahl[2];
        if (t) {
            #pragma unroll
            for (int q = 0; q < 2; q++) {
                const float* hp_ = &lds_h[woff + lx * 68 + q * 32 + quad * 8];
                float4 v0 = *(const float4*)hp_;
                float4 v1 = *(const float4*)(hp_ + 4);
                float fv[8] = {v0.x, v0.y, v0.z, v0.w, v1.x, v1.y, v1.z, v1.w};
                hilo8(fv, ahh[q], ahl[q]);
            }
        }

        f4v accR[4], accZ[4], accNx[4], accNh[4];
        #pragma unroll
        for (int j = 0; j < 4; j++) {
            accR[j]  = mfma16(axh, w1f[j],     mfma16(axl, w1f[j],     bR[j]));
            accZ[j]  = mfma16(axh, w1f[j + 4], mfma16(axl, w1f[j + 4], bZ[j]));
            accNx[j] = mfma16(axh, w1f[j + 8], mfma16(axl, w1f[j + 8], bNx[j]));
            accNh[j] = (f4v){bHn[j], bHn[j], bHn[j], bHn[j]};
        }
        if (t) {
            #pragma unroll
            for (int j = 0; j < 4; j++) {
                #pragma unroll
                for (int q = 0; q < 2; q++) {
                    int4 bRf = *(const int4*)&lds_B[((j * 2 + q) * 64 + ln) * 4];
                    int4 bZf = *(const int4*)&lds_B[(((j + 4) * 2 + q) * 64 + ln) * 4];
                    int4 bNf = *(const int4*)&lds_B[(((j + 8) * 2 + q) * 64 + ln) * 4];
                    accR[j]  = mfma16(ahh[q], bRf, mfma16(ahl[q], bRf, accR[j]));
                    accZ[j]  = mfma16(ahh[q], bZf, mfma16(ahl[q], bZf, accZ[j]));
                    accNh[j] = mfma16(ahh[q], bNf, mfma16(ahl[q], bNf, accNh[j]));
                }
            }
        }

        // gates + h write (per-wave private LDS region; same-wave DS in-order)
        #pragma unroll
        for (int j = 0; j < 4; j++) {
            #pragma unroll
            for (int reg = 0; reg < 4; reg++) {
                float rr = 1.f / (1.f + __expf(-accR[j][reg]));
                float zz = 1.f / (1.f + __expf(-accZ[j][reg]));
                float pre = fmaf(rr, accNh[j][reg], accNx[j][reg]);
                pre = fminf(fmaxf(pre, -30.f), 30.f);
                float e2 = __expf(pre + pre);
                float nn = (e2 - 1.f) / (e2 + 1.f);
                float hv = (1.f - zz) * nn + zz * hp[j][reg];
                hp[j][reg] = hv;
                lds_h[woff + (quad * 4 + reg) * 68 + j * 16 + lx] = hv;
            }
        }
    }
    __syncthreads();   // all waves done writing their final h

    // epilogue: coalesced write to h_out in [n][b][64] layout
    {
        int row = ln >> 2, cc = (ln & 3) * 16;
        int m = m0 + wave * 16 + row;
        int b = m / NN; int n = m - b * NN;
        float* op = h_out + ((size_t)n * BB + b) * HH + cc;
        #pragma unroll
        for (int u = 0; u < 4; u++) {
            float4 v = *(const float4*)&lds_h[woff + row * 68 + cc + u * 4];
            *(float4*)(op + u * 4) = v;
        }
    }
}

// ---------------- diffusion: fwd + bwd in one kernel, [n][b][64] layout ----------------
// per edge: one contiguous 2 KB read; lane L owns floats 8L..8L+7 of the node slab
__global__ __launch_bounds__(256)
void prop2_k(const float* __restrict__ srcF, float* __restrict__ dstF,
             const int* __restrict__ ptrF, const int* __restrict__ nbrF,
             const float* __restrict__ wF,
             const float* __restrict__ srcB, float* __restrict__ dstB,
             const int* __restrict__ ptrB, const int* __restrict__ nbrB,
             const float* __restrict__ wB) {
    int node = blockIdx.x * 4 + (threadIdx.x >> 6);
    const int L = threadIdx.x & 63;
    const float* src; float* dst; const int* ptr; const int* nbr; const float* w;
    if (node < NN) {
        src = srcF; dst = dstF; ptr = ptrF; nbr = nbrF; w = wF;
    } else {
        node -= NN;
        src = srcB; dst = dstB; ptr = ptrB; nbr = nbrB; w = wB;
    }
    float acc[8] = {0.f,0.f,0.f,0.f,0.f,0.f,0.f,0.f};
    int e0 = ptr[node], e1 = ptr[node + 1];
    for (int e = e0; e < e1; e++) {
        int s = nbr[e]; float wv = w[e];
        const float* sp = src + (size_t)s * (BB * HH) + L * 8;
        float4 v0 = *(const float4*)sp;
        float4 v1 = *(const float4*)(sp + 4);
        acc[0] = fmaf(v0.x, wv, acc[0]); acc[1] = fmaf(v0.y, wv, acc[1]);
        acc[2] = fmaf(v0.z, wv, acc[2]); acc[3] = fmaf(v0.w, wv, acc[3]);
        acc[4] = fmaf(v1.x, wv, acc[4]); acc[5] = fmaf(v1.y, wv, acc[5]);
        acc[6] = fmaf(v1.z, wv, acc[6]); acc[7] = fmaf(v1.w, wv, acc[7]);
    }
    float* dp = dst + (size_t)node * (BB * HH) + L * 8;
    *(float4*)dp       = make_float4(acc[0], acc[1], acc[2], acc[3]);
    *(float4*)(dp + 4) = make_float4(acc[4], acc[5], acc[6], acc[7]);
}

// ---------------- fused filter (K=320) + decoder (K=64) ----------------
// sources are in [n][b][64] layout; output rows remain b-major for coalesced writes
__global__ __launch_bounds__(256, 2)
void filtdec_k(const float* __restrict__ h, const float* __restrict__ f1,
               const float* __restrict__ f2, const float* __restrict__ b1,
               const float* __restrict__ b2,
               const float* __restrict__ filtW, const float* __restrict__ filtb,
               const float* __restrict__ decW, const float* __restrict__ decb,
               float* __restrict__ out) {
    __shared__ float lds_in[64 * 100];
    __shared__ float lds_w[64 * 100];
    __shared__ float lds_z[64 * 68];
    const int tid = threadIdx.x;
    const int m0 = blockIdx.x * 64;
    const int c0 = (tid & 15) * 4, r0 = (tid >> 4) * 4;

    float acc[4][4];
    #pragma unroll
    for (int i = 0; i < 4; i++)
        #pragma unroll
        for (int j = 0; j < 4; j++) acc[i][j] = 0.f;

    #pragma unroll 1
    for (int q = 0; q < 5; q++) {
        const float* src = (q == 0) ? h : (q == 1) ? f1 : (q == 2) ? f2 : (q == 3) ? b1 : b2;
        {   // load input tile 64x64 fp32 (nb-layout rows)
            int row = tid >> 2, cc = (tid & 3) * 16;
            int m = m0 + row;
            int b = m / NN; int n = m - b * NN;
            const float* sp = src + ((size_t)n * BB + b) * HH + cc;
            float4 v0 = *(const float4*)(sp + 0);
            float4 v1 = *(const float4*)(sp + 4);
            float4 v2 = *(const float4*)(sp + 8);
            float4 v3 = *(const float4*)(sp + 12);
            *(float4*)&lds_in[row * 100 + cc + 0]  = v0;
            *(float4*)&lds_in[row * 100 + cc + 4]  = v1;
            *(float4*)&lds_in[row * 100 + cc + 8]  = v2;
            *(float4*)&lds_in[row * 100 + cc + 12] = v3;
        }
        {   // load filtW chunk rows q*64..
            int k = tid >> 2, cc = (tid & 3) * 16;
            const float* wp = filtW + (size_t)(q * 64 + k) * HH + cc;
            float4 v0 = *(const float4*)(wp + 0);
            float4 v1 = *(const float4*)(wp + 4);
            float4 v2 = *(const float4*)(wp + 8);
            float4 v3 = *(const float4*)(wp + 12);
            *(float4*)&lds_w[k * 100 + cc + 0]  = v0;
            *(float4*)&lds_w[k * 100 + cc + 4]  = v1;
            *(float4*)&lds_w[k * 100 + cc + 8]  = v2;
            *(float4*)&lds_w[k * 100 + cc + 12] = v3;
        }
        __syncthreads();
        #pragma unroll 4
        for (int k4 = 0; k4 < 64; k4 += 4) {
            float4 iv[4];
            #pragma unroll
            for (int i = 0; i < 4; i++)
                iv[i] = *(const float4*)&lds_in[(r0 + i) * 100 + k4];
            #pragma unroll
            for (int kk = 0; kk < 4; kk++) {
                const float4 wv = *(const float4*)&lds_w[(k4 + kk) * 100 + c0];
                #pragma unroll
                for (int i = 0; i < 4; i++) {
                    float a_ = f4c(iv[i], kk);
                    FMA4(acc[i], wv, a_);
                }
            }
        }
        __syncthreads();
    }
    {
        float fb[4];
        #pragma unroll
        for (int j = 0; j < 4; j++) fb[j] = filtb[c0 + j];
        #pragma unroll
        for (int i = 0; i < 4; i++)
            *(float4*)&lds_z[(r0 + i) * 68 + c0] =
                make_float4(acc[i][0] + fb[0], acc[i][1] + fb[1],
                            acc[i][2] + fb[2], acc[i][3] + fb[3]);
    }
    {   // load decW [64][96]
        int k = tid >> 2, cc = (tid & 3) * 24;
        const float* wp = decW + k * 96 + cc;
        float* dstp = &lds_w[k * 100 + cc];
        #pragma unroll
        for (int u = 0; u < 6; u++) {
            float4 v = *(const float4*)(wp + u * 4);
            *(float4*)(dstp + u * 4) = v;
        }
    }
    __syncthreads();

    const int c0b = (tid & 15) * 6;
    float acc2[4][6];
    #pragma unroll
    for (int i = 0; i < 4; i++)
        #pragma unroll
        for (int j = 0; j < 6; j++) acc2[i][j] = 0.f;
    #pragma unroll 4
    for (int k4 = 0; k4 < 64; k4 += 4) {
        float4 zv[4];
        #pragma unroll
        for (int i = 0; i < 4; i++)
            zv[i] = *(const float4*)&lds_z[(r0 + i) * 68 + k4];
        #pragma unroll
        for (int kk = 0; kk < 4; kk++) {
            float2 wa = *(const float2*)&lds_w[(k4 + kk) * 100 + c0b];
            float2 wb = *(const float2*)&lds_w[(k4 + kk) * 100 + c0b + 2];
            float2 wc = *(const float2*)&lds_w[(k4 + kk) * 100 + c0b + 4];
            #pragma unroll
            for (int i = 0; i < 4; i++) {
                float zz = f4c(zv[i], kk);
                acc2[i][0] = fmaf(zz, wa.x, acc2[i][0]);
                acc2[i][1] = fmaf(zz, wa.y, acc2[i][1]);
                acc2[i][2] = fmaf(zz, wb.x, acc2[i][2]);
                acc2[i][3] = fmaf(zz, wb.y, acc2[i][3]);
                acc2[i][4] = fmaf(zz, wc.x, acc2[i][4]);
                acc2[i][5] = fmaf(zz, wc.y, acc2[i][5]);
            }
        }
    }
    {
        float db[6];
        #pragma unroll
        for (int j = 0; j < 6; j++) db[j] = decb[c0b + j];
        #pragma unroll
        for (int i = 0; i < 4; i++)
            #pragma unroll
            for (int j = 0; j < 6; j++)
                lds_in[(r0 + i) * 100 + c0b + j] = acc2[i][j] + db[j];
    }
    __syncthreads();
    #pragma unroll 1
    for (int hor = 0; hor < HORZ; hor++) {
        int nl = tid >> 2, fp = tid & 3;
        int m = m0 + nl;
        int b = m / NN; int n = m - b * NN;
        float v0 = lds_in[nl * 100 + hor * 8 + 2 * fp];
        float v1 = lds_in[nl * 100 + hor * 8 + 2 * fp + 1];
        *(float2*)&out[(((size_t)b * HORZ + hor) * NN + n) * FF + 2 * fp] =
            make_float2(v0, v1);
    }
}

extern "C" void kernel_launch(void* const* d_in, const int* in_sizes, int n_in,
                              void* d_out, int out_size, void* d_ws, size_t ws_size,
                              hipStream_t stream) {
    (void)in_sizes; (void)n_in; (void)out_size; (void)ws_size;
    const float* x     = (const float*)d_in[0];
    const int*   ei    = (const int*)d_in[1];
    const float* ew    = (const float*)d_in[2];
    const float* encW  = (const float*)d_in[3];
    const float* encb  = (const float*)d_in[4];
    const float* emb   = (const float*)d_in[5];
    const float* wih   = (const float*)d_in[6];
    const float* whh   = (const float*)d_in[7];
    const float* bih   = (const float*)d_in[8];
    const float* bhh   = (const float*)d_in[9];
    const float* filtW = (const float*)d_in[10];
    const float* filtb = (const float*)d_in[11];
    const float* decW  = (const float*)d_in[12];
    const float* decb  = (const float*)d_in[13];
    float* out = (float*)d_out;

    float* ws = (float*)d_ws;
    float* h    = ws + OFF_H;
    float* f1   = ws + OFF_F1;
    float* f2   = ws + OFF_F2;
    float* b1   = ws + OFF_B1;
    float* b2   = ws + OFF_B2;
    float* bias = ws + OFF_BIAS;
    float* W1   = ws + OFF_W1;
    float* degf = ws + OFF_DEGF;
    float* degb = ws + OFF_DEGB;
    int* cntf = (int*)(ws + OFF_CNTF);
    int* cntb = (int*)(ws + OFF_CNTB);
    int* ptrf = (int*)(ws + OFF_PTRF);
    int* ptrb = (int*)(ws + OFF_PTRB);
    int* srcf = (int*)(ws + OFF_SRCF);
    int* srcb = (int*)(ws + OFF_SRCB);
    float* wf = ws + OFF_WF;
    float* wb = ws + OFF_WB;
    int* flag = (int*)(ws + OFF_FLAG);

    flag_k<<<1, 64, 0, stream>>>(ei, flag);
    zero_k<<<(40000 + 255) / 256, 256, 0, stream>>>(degf, 40000);
    csr_count_k<<<EE / 256, 256, 0, stream>>>(ei, ew, flag, cntf, cntb, degf, degb);
    scan_k<<<2, 256, 0, stream>>>(cntf, cntb, ptrf, ptrb);
    csr_fill_k<<<EE / 256, 256, 0, stream>>>(ei, ew, flag, degf, degb, ptrf, ptrb,
                                             cntf, cntb, srcf, srcb, wf, wb);
    w1_k<<<(FF * GG + 255) / 256, 256, 0, stream>>>(encW, wih, W1);
    biasA_k<<<(NN + 63) / 64, 256, 0, stream>>>(emb, encb, wih, bih, bhh, bias);
    gru_k<<<MM / 64, 256, 0, stream>>>(x, bias, W1, whh, bhh, h);
    prop2_k<<<(2 * NN) / 4, 256, 0, stream>>>(h,  f1, ptrf, srcf, wf,
                                              h,  b1, ptrb, srcb, wb);
    prop2_k<<<(2 * NN) / 4, 256, 0, stream>>>(f1, f2, ptrf, srcf, wf,
                                              b1, b2, ptrb, srcb, wb);
    filtdec_k<<<MM / 64, 256, 0, stream>>>(h, f1, f2, b1, b2,
                                           filtW, filtb, decW, decb, out);
}